// Round 1
// baseline (1284.466 us; speedup 1.0000x reference)
//
#include <hip/hip_runtime.h>

// ---------------------------------------------------------------------------
// KronFTLinear: out = x@W^T + b + sum_p g[n,p] * (x @ (150*kron(A_p,B_p))^T)
//   A_p = Re(ifft2(scatter(spectrum_p)))  (2048x2048, 1000 nonzeros)
//   Kron trick: out_p[n,2r+a] = 150 * sum_c A_p[r,c]*y_pa[n,c],
//               y_pa[n,c] = B_p[a,0]*x[n,2c] + B_p[a,1]*x[n,2c+1]
//   A_p built as bf16 GEMM over cos/sin rank-1 tables (K=2000 pad 2048).
// Workspace layout (256 MiB needed):
//   [0,64K)      g[8192][2] f32
//   [64K,96K)    gate_m[2][4096] f32
//   [1M,17M)     Ascaled[2][2048][2048] bf16  (150/2^22 folded in)
//   [32M,96M)    xb[8192][4096] bf16
//   [96M,128M)   bwb[4096][4096] bf16
//   [128M,256M)  Yb[4][8192][2048] bf16   (p*2+a)
//   [128M,160M)  trig tables (overlap Yb; consumed by A-GEMM before Yb write)
// ---------------------------------------------------------------------------

#define AS1 __attribute__((address_space(1)))
#define AS3 __attribute__((address_space(3)))

using bf16x8   = __attribute__((ext_vector_type(8))) __bf16;
using f32x4    = __attribute__((ext_vector_type(4))) float;
using ushort8v = __attribute__((ext_vector_type(8))) unsigned short;
using ushort4v = __attribute__((ext_vector_type(4))) unsigned short;

__device__ __forceinline__ unsigned short f2bf(float f) {
  unsigned int u = __float_as_uint(f);
  u += 0x7FFFu + ((u >> 16) & 1u);   // round-to-nearest-even
  return (unsigned short)(u >> 16);
}

__device__ __forceinline__ void gll16(void* lds, const void* g) {
  // async global->LDS, 16B/lane, dest = wave-uniform base + lane*16
  __builtin_amdgcn_global_load_lds((AS1 void*)(g), (AS3 void*)(lds), 16, 0, 0);
}

// ---------------- prep: gate_m[e][d] = (1/8192) sum_k gp*(-1)^(e*ek)*cos(2pi d*dk/4096)
__global__ void k_gatem(const float* __restrict__ gp, const int* __restrict__ gidx,
                        float* __restrict__ gatem, int NG) {
  int t = blockIdx.x * 256 + threadIdx.x;    // 8192 threads
  int e = t >> 12, d = t & 4095;
  float acc = 0.f;
  for (int k = 0; k < NG; k++) {
    int iv = gidx[k];
    int dk = iv & 4095;
    float th = (float)((d * dk) & 4095) * 1.5339807878856412e-3f;  // 2pi/4096
    float cv = __cosf(th);
    float v = gp[k] * cv;
    acc += ((e & (iv >> 12)) & 1) ? -v : v;
  }
  gatem[t] = acc * (1.f / 8192.f);
}

// ---------------- prep: trig tables, z = p*2 + isQ; [z][r(2048)][kk(2048)] bf16
__global__ void k_tables(const float* __restrict__ spec, const int* __restrict__ idx,
                         unsigned short* __restrict__ tbl, int NFP) {
  int z = blockIdx.y;
  int p = z >> 1, isQ = z & 1;
  int t = blockIdx.x * 256 + threadIdx.x;    // 2048*2048 per table
  int r = t >> 11, kk = t & 2047;
  unsigned short v = 0;
  if (kk < 2 * NFP) {
    int j = (kk < NFP) ? kk : kk - NFP;
    int iv = idx[p * NFP + j];
    int f = isQ ? (iv & 2047) : (iv >> 11);  // ck : rk
    float th = (float)((r * f) & 2047) * 3.0679615757712823e-3f;   // 2pi/2048
    float val = (kk < NFP) ? __cosf(th) : __sinf(th);
    if (isQ) {
      float s = spec[p * NFP + j];
      val *= (kk < NFP) ? s : -s;            // A = P_cos Q_cos^T - P_sin Q_sin^T
    }
    v = f2bf(val);
  }
  tbl[(size_t)z * 4194304 + t] = v;
}

// ---------------- prep: gate logits GEMV + softmax -> g[n][2]
__global__ void k_gate(const float* __restrict__ x, const float* __restrict__ gatem,
                       float* __restrict__ g) {
  int n = blockIdx.x * 4 + (threadIdx.x >> 6);
  int l = threadIdx.x & 63;
  const float4* xr  = (const float4*)(x + (size_t)n * 4096);
  const float4* g0p = (const float4*)(gatem);
  const float4* g1p = (const float4*)(gatem + 4096);
  float s0 = 0.f, s1 = 0.f;
  for (int t = 0; t < 16; t++) {
    int ii = l + (t << 6);
    float4 xv = xr[ii], a = g0p[ii], b = g1p[ii];
    s0 += xv.x * a.x + xv.y * a.y + xv.z * a.z + xv.w * a.w;
    s1 += xv.x * b.x + xv.y * b.y + xv.z * b.z + xv.w * b.w;
  }
  for (int off = 32; off > 0; off >>= 1) {
    s0 += __shfl_down(s0, off);
    s1 += __shfl_down(s1, off);
  }
  if (l == 0) {
    float mx = fmaxf(s0, s1);
    float e0 = __expf(s0 - mx), e1 = __expf(s1 - mx);
    float inv = 1.f / (e0 + e1);
    g[2 * n] = e0 * inv;
    g[2 * n + 1] = e1 * inv;
  }
}

// ---------------- prep: x -> xb bf16, and Y[(p,a)][n][c] = B[p,a,0]x[n,2c]+B[p,a,1]x[n,2c+1]
__global__ void k_convx(const float* __restrict__ x, unsigned short* __restrict__ xb,
                        unsigned short* __restrict__ Yb, const float* __restrict__ Bl) {
  size_t t = (size_t)blockIdx.x * 256 + threadIdx.x;   // < 4194304, 8 elems each
  const float4* xp = (const float4*)x + t * 2;
  float4 v0 = xp[0], v1 = xp[1];
  ushort8v xv;
  xv[0]=f2bf(v0.x); xv[1]=f2bf(v0.y); xv[2]=f2bf(v0.z); xv[3]=f2bf(v0.w);
  xv[4]=f2bf(v1.x); xv[5]=f2bf(v1.y); xv[6]=f2bf(v1.z); xv[7]=f2bf(v1.w);
  *(ushort8v*)(xb + t * 8) = xv;
  float xe[4] = {v0.x, v0.z, v1.x, v1.z};
  float xo[4] = {v0.y, v0.w, v1.y, v1.w};
  #pragma unroll
  for (int pa = 0; pa < 4; pa++) {
    float b0 = Bl[pa * 2], b1 = Bl[pa * 2 + 1];
    ushort4v yv;
    #pragma unroll
    for (int c = 0; c < 4; c++) yv[c] = f2bf(b0 * xe[c] + b1 * xo[c]);
    *(ushort4v*)(Yb + (size_t)pa * 16777216 + t * 4) = yv;
  }
}

// ---------------- prep: base_w -> bf16
__global__ void k_convw(const float* __restrict__ w, unsigned short* __restrict__ wb) {
  size_t t = (size_t)blockIdx.x * 256 + threadIdx.x;   // < 2097152
  const float4* sp = (const float4*)w + t * 2;
  float4 v0 = sp[0], v1 = sp[1];
  ushort8v o;
  o[0]=f2bf(v0.x); o[1]=f2bf(v0.y); o[2]=f2bf(v0.z); o[3]=f2bf(v0.w);
  o[4]=f2bf(v1.x); o[5]=f2bf(v1.y); o[6]=f2bf(v1.z); o[7]=f2bf(v1.w);
  *(ushort8v*)(wb + t * 8) = o;
}

// ---------------- shared MFMA GEMM core: C(128x128) += A(128xK) * B(128xK)^T
// LDS chunk XOR-swizzle (q^=(r>>1)&3) so frag ds_read_b128 is only 2-way aliased (free).
__device__ __forceinline__ void gemm_core(
    const unsigned short* __restrict__ Amat, int lda,   // already offset to tile row 0
    const unsigned short* __restrict__ Bmat, int ldb,
    int K, char* As, char* Bs, f32x4 acc[4][4]) {
  const int tid = threadIdx.x;
  const int w = tid >> 6, l = tid & 63;
  const int quad = l >> 4, l15 = l & 15;
  const int wm = (w >> 1) << 6, wn = (w & 1) << 6;

  int c1 = (w << 6) + l, c2 = c1 + 256;                 // 16B-chunk ids (512 total)
  int r1 = c1 >> 2, q1 = (c1 & 3) ^ ((r1 >> 1) & 3);
  int r2 = c2 >> 2, q2 = (c2 & 3) ^ ((r2 >> 1) & 3);
  const unsigned short* aS1 = Amat + (size_t)r1 * lda + (q1 << 3);
  const unsigned short* aS2 = Amat + (size_t)r2 * lda + (q2 << 3);
  const unsigned short* bS1 = Bmat + (size_t)r1 * ldb + (q1 << 3);
  const unsigned short* bS2 = Bmat + (size_t)r2 * ldb + (q2 << 3);
  char* aD1 = As + (w << 10);
  char* aD2 = As + 4096 + (w << 10);
  char* bD1 = Bs + (w << 10);
  char* bD2 = Bs + 4096 + (w << 10);

  int aOff[4], bOff[4];
  #pragma unroll
  for (int i = 0; i < 4; i++) {
    int ra = wm + (i << 4) + l15;
    aOff[i] = (ra << 6) + ((quad ^ ((ra >> 1) & 3)) << 4);
    int rb = wn + (i << 4) + l15;
    bOff[i] = (rb << 6) + ((quad ^ ((rb >> 1) & 3)) << 4);
  }

  for (int kt = 0; kt < K; kt += 32) {
    __syncthreads();
    gll16(aD1, aS1); gll16(aD2, aS2);
    gll16(bD1, bS1); gll16(bD2, bS2);
    __syncthreads();
    bf16x8 af[4], bfv[4];
    #pragma unroll
    for (int i = 0; i < 4; i++) af[i]  = *(const bf16x8*)(As + aOff[i]);
    #pragma unroll
    for (int j = 0; j < 4; j++) bfv[j] = *(const bf16x8*)(Bs + bOff[j]);
    #pragma unroll
    for (int i = 0; i < 4; i++)
      #pragma unroll
      for (int j = 0; j < 4; j++)
        acc[i][j] = __builtin_amdgcn_mfma_f32_16x16x32_bf16(af[i], bfv[j], acc[i][j], 0, 0, 0);
    aS1 += 32; aS2 += 32; bS1 += 32; bS2 += 32;
  }
}

// ---------------- A-build GEMM: Ascaled[p] = (150/2^22) * P_p @ Q_p^T  (bf16 out)
__global__ __launch_bounds__(256, 2) void k_abuild(
    const unsigned short* __restrict__ tbl, unsigned short* __restrict__ Asc) {
  __shared__ __align__(16) char sm[16384];
  const int p = blockIdx.z;
  const unsigned short* P = tbl + (size_t)(2 * p) * 4194304;
  const unsigned short* Q = tbl + (size_t)(2 * p + 1) * 4194304;
  f32x4 acc[4][4];
  #pragma unroll
  for (int i = 0; i < 4; i++)
    #pragma unroll
    for (int j = 0; j < 4; j++) acc[i][j] = (f32x4){0.f, 0.f, 0.f, 0.f};
  const int m0 = blockIdx.x << 7, n0 = blockIdx.y << 7;
  gemm_core(P + (size_t)m0 * 2048, 2048, Q + (size_t)n0 * 2048, 2048, 2048,
            sm, sm + 8192, acc);
  const int tid = threadIdx.x, w = tid >> 6, l = tid & 63;
  const int quad = l >> 4, l15 = l & 15;
  const int wm = (w >> 1) << 6, wn = (w & 1) << 6;
  const float SC = 150.f / 4194304.f;
  unsigned short* Ap = Asc + (size_t)p * 4194304;
  #pragma unroll
  for (int j = 0; j < 4; j++) {
    int c = n0 + wn + (j << 4) + l15;
    #pragma unroll
    for (int i = 0; i < 4; i++) {
      int rb = m0 + wm + (i << 4) + (quad << 2);
      #pragma unroll
      for (int reg = 0; reg < 4; reg++)
        Ap[(size_t)(rb + reg) * 2048 + c] = f2bf(acc[i][j][reg] * SC);
    }
  }
}

// ---------------- base GEMM: out = xb @ bwb^T + bias
__global__ __launch_bounds__(256, 2) void k_base(
    const unsigned short* __restrict__ xb, const unsigned short* __restrict__ wb,
    const float* __restrict__ bias, float* __restrict__ out) {
  __shared__ __align__(16) char sm[16384];
  f32x4 acc[4][4];
  #pragma unroll
  for (int i = 0; i < 4; i++)
    #pragma unroll
    for (int j = 0; j < 4; j++) acc[i][j] = (f32x4){0.f, 0.f, 0.f, 0.f};
  const int m0 = blockIdx.x << 7, n0 = blockIdx.y << 7;
  gemm_core(xb + (size_t)m0 * 4096, 4096, wb + (size_t)n0 * 4096, 4096, 4096,
            sm, sm + 8192, acc);
  const int tid = threadIdx.x, w = tid >> 6, l = tid & 63;
  const int quad = l >> 4, l15 = l & 15;
  const int wm = (w >> 1) << 6, wn = (w & 1) << 6;
  #pragma unroll
  for (int j = 0; j < 4; j++) {
    int o = n0 + wn + (j << 4) + l15;
    float bv = bias[o];
    #pragma unroll
    for (int i = 0; i < 4; i++) {
      int mb = m0 + wm + (i << 4) + (quad << 2);
      #pragma unroll
      for (int reg = 0; reg < 4; reg++)
        out[(size_t)(mb + reg) * 4096 + o] = acc[i][j][reg] + bv;
    }
  }
}

// ---------------- pack GEMM: out[n,2r+a] += sum_p g[n,p] * (Y_pa @ Ascaled_p^T)[n,r]
__global__ __launch_bounds__(256, 2) void k_pack(
    const unsigned short* __restrict__ Yb, const unsigned short* __restrict__ Asc,
    const float* __restrict__ g, float* __restrict__ out) {
  __shared__ __align__(16) char sm[20480];
  char* Y0s = sm; char* Y1s = sm + 8192; char* Bqs = sm + 16384;
  const int tid = threadIdx.x, w = tid >> 6, l = tid & 63;
  const int quad = l >> 4, l15 = l & 15;
  const int m0 = blockIdx.x << 7, r0 = blockIdx.y << 6;
  const int wm = (w >> 1) << 6, wr = (w & 1) << 5;

  int c1 = (w << 6) + l, c2 = c1 + 256;
  int r1 = c1 >> 2, q1 = (c1 & 3) ^ ((r1 >> 1) & 3);
  int r2 = c2 >> 2, q2 = (c2 & 3) ^ ((r2 >> 1) & 3);

  int yOff[4], bOff[2];
  #pragma unroll
  for (int i = 0; i < 4; i++) {
    int ra = wm + (i << 4) + l15;
    yOff[i] = (ra << 6) + ((quad ^ ((ra >> 1) & 3)) << 4);
  }
  #pragma unroll
  for (int j = 0; j < 2; j++) {
    int rb = wr + (j << 4) + l15;
    bOff[j] = (rb << 6) + ((quad ^ ((rb >> 1) & 3)) << 4);
  }

  f32x4 accf[2][4][2];
  #pragma unroll
  for (int a = 0; a < 2; a++)
    #pragma unroll
    for (int i = 0; i < 4; i++)
      #pragma unroll
      for (int j = 0; j < 2; j++) accf[a][i][j] = (f32x4){0.f, 0.f, 0.f, 0.f};

  for (int p = 0; p < 2; p++) {
    const unsigned short* Y0 = Yb + (size_t)(2 * p) * 16777216 + (size_t)m0 * 2048;
    const unsigned short* Y1 = Yb + (size_t)(2 * p + 1) * 16777216 + (size_t)m0 * 2048;
    const unsigned short* Bq = Asc + (size_t)p * 4194304 + (size_t)r0 * 2048;
    const unsigned short* y0S1 = Y0 + (size_t)r1 * 2048 + (q1 << 3);
    const unsigned short* y0S2 = Y0 + (size_t)r2 * 2048 + (q2 << 3);
    const unsigned short* y1S1 = Y1 + (size_t)r1 * 2048 + (q1 << 3);
    const unsigned short* y1S2 = Y1 + (size_t)r2 * 2048 + (q2 << 3);
    const unsigned short* bS1  = Bq + (size_t)r1 * 2048 + (q1 << 3);  // 64-row tile

    f32x4 accc[2][4][2];
    #pragma unroll
    for (int a = 0; a < 2; a++)
      #pragma unroll
      for (int i = 0; i < 4; i++)
        #pragma unroll
        for (int j = 0; j < 2; j++) accc[a][i][j] = (f32x4){0.f, 0.f, 0.f, 0.f};

    for (int kt = 0; kt < 2048; kt += 32) {
      __syncthreads();
      gll16(Y0s + (w << 10), y0S1); gll16(Y0s + 4096 + (w << 10), y0S2);
      gll16(Y1s + (w << 10), y1S1); gll16(Y1s + 4096 + (w << 10), y1S2);
      gll16(Bqs + (w << 10), bS1);
      __syncthreads();
      bf16x8 yf0[4], yf1[4], bfr[2];
      #pragma unroll
      for (int i = 0; i < 4; i++) {
        yf0[i] = *(const bf16x8*)(Y0s + yOff[i]);
        yf1[i] = *(const bf16x8*)(Y1s + yOff[i]);
      }
      #pragma unroll
      for (int j = 0; j < 2; j++) bfr[j] = *(const bf16x8*)(Bqs + bOff[j]);
      #pragma unroll
      for (int i = 0; i < 4; i++)
        #pragma unroll
        for (int j = 0; j < 2; j++) {
          accc[0][i][j] = __builtin_amdgcn_mfma_f32_16x16x32_bf16(yf0[i], bfr[j], accc[0][i][j], 0, 0, 0);
          accc[1][i][j] = __builtin_amdgcn_mfma_f32_16x16x32_bf16(yf1[i], bfr[j], accc[1][i][j], 0, 0, 0);
        }
      y0S1 += 32; y0S2 += 32; y1S1 += 32; y1S2 += 32; bS1 += 32;
    }
    // gate-weighted accumulate (g depends on row n)
    #pragma unroll
    for (int i = 0; i < 4; i++)
      #pragma unroll
      for (int reg = 0; reg < 4; reg++) {
        int n = m0 + wm + (i << 4) + (quad << 2) + reg;
        float gv = g[2 * n + p];
        #pragma unroll
        for (int a = 0; a < 2; a++)
          #pragma unroll
          for (int j = 0; j < 2; j++)
            accf[a][i][j][reg] += gv * accc[a][i][j][reg];
      }
  }
  // RMW epilogue: o = 2r + a -> (even,odd) pair = contiguous float2 per lane
  #pragma unroll
  for (int i = 0; i < 4; i++)
    #pragma unroll
    for (int reg = 0; reg < 4; reg++) {
      size_t n = m0 + wm + (i << 4) + (quad << 2) + reg;
      #pragma unroll
      for (int j = 0; j < 2; j++) {
        int r = r0 + wr + (j << 4) + l15;
        float2* po = (float2*)(out + n * 4096 + 2 * r);
        float2 v = *po;
        v.x += accf[0][i][j][reg];
        v.y += accf[1][i][j][reg];
        *po = v;
      }
    }
}

// ---------------------------------------------------------------------------
extern "C" void kernel_launch(void* const* d_in, const int* in_sizes, int n_in,
                              void* d_out, int out_size, void* d_ws, size_t ws_size,
                              hipStream_t stream) {
  const float* x    = (const float*)d_in[0];
  const float* basw = (const float*)d_in[1];
  const float* basb = (const float*)d_in[2];
  const float* spec = (const float*)d_in[3];
  const float* Bl   = (const float*)d_in[4];
  const float* gp   = (const float*)d_in[5];
  const int*   idx  = (const int*)d_in[6];
  const int*   gidx = (const int*)d_in[7];
  const int NFP = in_sizes[3] / 2;   // 1000
  const int NG  = in_sizes[5];       // 819

  char* ws = (char*)d_ws;
  float*          gbuf  = (float*)(ws);
  float*          gatem = (float*)(ws + (64ull << 10));
  unsigned short* Asc   = (unsigned short*)(ws + (1ull << 20));
  unsigned short* xb    = (unsigned short*)(ws + (32ull << 20));
  unsigned short* bwb   = (unsigned short*)(ws + (96ull << 20));
  unsigned short* Yb    = (unsigned short*)(ws + (128ull << 20));
  unsigned short* tbl   = (unsigned short*)(ws + (128ull << 20)); // overlaps Yb (ordered)
  float* outp = (float*)d_out;

  k_gatem <<<32, 256, 0, stream>>>(gp, gidx, gatem, NG);
  k_tables<<<dim3(16384, 4), 256, 0, stream>>>(spec, idx, tbl, NFP);
  k_abuild<<<dim3(16, 16, 2), 256, 0, stream>>>(tbl, Asc);       // reads tbl
  k_convx <<<16384, 256, 0, stream>>>(x, xb, Yb, Bl);            // overwrites tbl region
  k_convw <<<8192, 256, 0, stream>>>(basw, bwb);
  k_gate  <<<2048, 256, 0, stream>>>(x, gatem, gbuf);
  k_base  <<<dim3(64, 32), 256, 0, stream>>>(xb, bwb, basb, outp);
  k_pack  <<<dim3(64, 32), 256, 0, stream>>>(Yb, Asc, gbuf, outp);
  (void)n_in; (void)out_size; (void)ws_size;
}

// Round 2
// 1184.267 us; speedup vs baseline: 1.0846x; 1.0846x over previous
//
#include <hip/hip_runtime.h>

// ---------------------------------------------------------------------------
// KronFTLinear: out = x@W^T + b + sum_p g[n,p] * (x @ (150*kron(A_p,B_p))^T)
//   Kron trick: out_p[n,2r+a] = 150 * sum_c A_p[r,c]*y_pa[n,c],
//               y_pa[n,c] = B_p[a,0]*x[n,2c] + B_p[a,1]*x[n,2c+1]
//   R1: gate folded into Y (Yg = g[n,p]*Y), p concatenated along K:
//       out_pack[n,2r+a] = sum_{k<4096} Zg_a[n,k] * Acat[r,k]
//       Zg_a[n, p*2048+c] = g[n,p]*y_pa[n,c];  Acat[r, p*2048+c] = Asc_p[r,c]
//   -> single-accumulator GEMM, no gate epilogue, 16KiB staged / 16 MFMA.
// Workspace layout (256 MiB):
//   [0,64K)      g[8192][2] f32
//   [64K,96K)    gate_m[2][4096] f32
//   [1M,17M)     Acat[2048][4096] bf16  (150/2^22 folded in)
//   [32M,96M)    xb[8192][4096] bf16
//   [96M,128M)   bwb[4096][4096] bf16
//   [128M,256M)  Zg[2][8192][4096] bf16   (index: a)
//   [128M,160M)  trig tables (overlap Zg; consumed by k_abuild before k_convx)
// ---------------------------------------------------------------------------

#define AS1 __attribute__((address_space(1)))
#define AS3 __attribute__((address_space(3)))

using bf16x8   = __attribute__((ext_vector_type(8))) __bf16;
using f32x4    = __attribute__((ext_vector_type(4))) float;
using ushort8v = __attribute__((ext_vector_type(8))) unsigned short;
using ushort4v = __attribute__((ext_vector_type(4))) unsigned short;

__device__ __forceinline__ unsigned short f2bf(float f) {
  unsigned int u = __float_as_uint(f);
  u += 0x7FFFu + ((u >> 16) & 1u);   // round-to-nearest-even
  return (unsigned short)(u >> 16);
}

__device__ __forceinline__ void gll16(void* lds, const void* g) {
  __builtin_amdgcn_global_load_lds((AS1 void*)(g), (AS3 void*)(lds), 16, 0, 0);
}

// ---------------- prep: gate_m[e][d]
__global__ void k_gatem(const float* __restrict__ gp, const int* __restrict__ gidx,
                        float* __restrict__ gatem, int NG) {
  int t = blockIdx.x * 256 + threadIdx.x;    // 8192 threads
  int e = t >> 12, d = t & 4095;
  float acc = 0.f;
  for (int k = 0; k < NG; k++) {
    int iv = gidx[k];
    int dk = iv & 4095;
    float th = (float)((d * dk) & 4095) * 1.5339807878856412e-3f;  // 2pi/4096
    float cv = __cosf(th);
    float v = gp[k] * cv;
    acc += ((e & (iv >> 12)) & 1) ? -v : v;
  }
  gatem[t] = acc * (1.f / 8192.f);
}

// ---------------- prep: trig tables, z = p*2 + isQ; [z][r(2048)][kk(2048)] bf16
__global__ void k_tables(const float* __restrict__ spec, const int* __restrict__ idx,
                         unsigned short* __restrict__ tbl, int NFP) {
  int z = blockIdx.y;
  int p = z >> 1, isQ = z & 1;
  int t = blockIdx.x * 256 + threadIdx.x;
  int r = t >> 11, kk = t & 2047;
  unsigned short v = 0;
  if (kk < 2 * NFP) {
    int j = (kk < NFP) ? kk : kk - NFP;
    int iv = idx[p * NFP + j];
    int f = isQ ? (iv & 2047) : (iv >> 11);
    float th = (float)((r * f) & 2047) * 3.0679615757712823e-3f;   // 2pi/2048
    float val = (kk < NFP) ? __cosf(th) : __sinf(th);
    if (isQ) {
      float s = spec[p * NFP + j];
      val *= (kk < NFP) ? s : -s;            // A = P_cos Q_cos^T - P_sin Q_sin^T
    }
    v = f2bf(val);
  }
  tbl[(size_t)z * 4194304 + t] = v;
}

// ---------------- prep: gate logits GEMV + softmax -> g[n][2]
__global__ void k_gate(const float* __restrict__ x, const float* __restrict__ gatem,
                       float* __restrict__ g) {
  int n = blockIdx.x * 4 + (threadIdx.x >> 6);
  int l = threadIdx.x & 63;
  const float4* xr  = (const float4*)(x + (size_t)n * 4096);
  const float4* g0p = (const float4*)(gatem);
  const float4* g1p = (const float4*)(gatem + 4096);
  float s0 = 0.f, s1 = 0.f;
  for (int t = 0; t < 16; t++) {
    int ii = l + (t << 6);
    float4 xv = xr[ii], a = g0p[ii], b = g1p[ii];
    s0 += xv.x * a.x + xv.y * a.y + xv.z * a.z + xv.w * a.w;
    s1 += xv.x * b.x + xv.y * b.y + xv.z * b.z + xv.w * b.w;
  }
  for (int off = 32; off > 0; off >>= 1) {
    s0 += __shfl_down(s0, off);
    s1 += __shfl_down(s1, off);
  }
  if (l == 0) {
    float mx = fmaxf(s0, s1);
    float e0 = __expf(s0 - mx), e1 = __expf(s1 - mx);
    float inv = 1.f / (e0 + e1);
    g[2 * n] = e0 * inv;
    g[2 * n + 1] = e1 * inv;
  }
}

// ---------------- prep: x->xb bf16; Zg[a][n][p*2048+c] = g[n,p]*(B[p,a,0]x[n,2c]+B[p,a,1]x[n,2c+1])
__global__ void k_convx(const float* __restrict__ x, unsigned short* __restrict__ xb,
                        unsigned short* __restrict__ Zg, const float* __restrict__ Bl,
                        const float* __restrict__ g) {
  size_t t = (size_t)blockIdx.x * 256 + threadIdx.x;   // < 4194304, 8 elems each
  const float4* xp = (const float4*)x + t * 2;
  float4 v0 = xp[0], v1 = xp[1];
  ushort8v xv;
  xv[0]=f2bf(v0.x); xv[1]=f2bf(v0.y); xv[2]=f2bf(v0.z); xv[3]=f2bf(v0.w);
  xv[4]=f2bf(v1.x); xv[5]=f2bf(v1.y); xv[6]=f2bf(v1.z); xv[7]=f2bf(v1.w);
  *(ushort8v*)(xb + t * 8) = xv;
  int n = (int)(t >> 9);
  int c0 = ((int)t & 511) * 4;
  float gg[2] = {g[2 * n], g[2 * n + 1]};
  float xe[4] = {v0.x, v0.z, v1.x, v1.z};
  float xo[4] = {v0.y, v0.w, v1.y, v1.w};
  #pragma unroll
  for (int pa = 0; pa < 4; pa++) {
    int p = pa >> 1, a = pa & 1;
    float b0 = Bl[pa * 2] * gg[p], b1 = Bl[pa * 2 + 1] * gg[p];
    ushort4v yv;
    #pragma unroll
    for (int c = 0; c < 4; c++) yv[c] = f2bf(b0 * xe[c] + b1 * xo[c]);
    *(ushort4v*)(Zg + (size_t)a * 33554432 + (size_t)n * 4096 + p * 2048 + c0) = yv;
  }
}

// ---------------- prep: base_w -> bf16
__global__ void k_convw(const float* __restrict__ w, unsigned short* __restrict__ wb) {
  size_t t = (size_t)blockIdx.x * 256 + threadIdx.x;   // < 2097152
  const float4* sp = (const float4*)w + t * 2;
  float4 v0 = sp[0], v1 = sp[1];
  ushort8v o;
  o[0]=f2bf(v0.x); o[1]=f2bf(v0.y); o[2]=f2bf(v0.z); o[3]=f2bf(v0.w);
  o[4]=f2bf(v1.x); o[5]=f2bf(v1.y); o[6]=f2bf(v1.z); o[7]=f2bf(v1.w);
  *(ushort8v*)(wb + t * 8) = o;
}

// ---------------- shared MFMA GEMM core: C(128x128) += A(128xK) * B(128xK)^T
__device__ __forceinline__ void gemm_core(
    const unsigned short* __restrict__ Amat, int lda,
    const unsigned short* __restrict__ Bmat, int ldb,
    int K, char* As, char* Bs, f32x4 acc[4][4]) {
  const int tid = threadIdx.x;
  const int w = tid >> 6, l = tid & 63;
  const int quad = l >> 4, l15 = l & 15;
  const int wm = (w >> 1) << 6, wn = (w & 1) << 6;

  int c1 = (w << 6) + l, c2 = c1 + 256;
  int r1 = c1 >> 2, q1 = (c1 & 3) ^ ((r1 >> 1) & 3);
  int r2 = c2 >> 2, q2 = (c2 & 3) ^ ((r2 >> 1) & 3);
  const unsigned short* aS1 = Amat + (size_t)r1 * lda + (q1 << 3);
  const unsigned short* aS2 = Amat + (size_t)r2 * lda + (q2 << 3);
  const unsigned short* bS1 = Bmat + (size_t)r1 * ldb + (q1 << 3);
  const unsigned short* bS2 = Bmat + (size_t)r2 * ldb + (q2 << 3);
  char* aD1 = As + (w << 10);
  char* aD2 = As + 4096 + (w << 10);
  char* bD1 = Bs + (w << 10);
  char* bD2 = Bs + 4096 + (w << 10);

  int aOff[4], bOff[4];
  #pragma unroll
  for (int i = 0; i < 4; i++) {
    int ra = wm + (i << 4) + l15;
    aOff[i] = (ra << 6) + ((quad ^ ((ra >> 1) & 3)) << 4);
    int rb = wn + (i << 4) + l15;
    bOff[i] = (rb << 6) + ((quad ^ ((rb >> 1) & 3)) << 4);
  }

  for (int kt = 0; kt < K; kt += 32) {
    __syncthreads();
    gll16(aD1, aS1); gll16(aD2, aS2);
    gll16(bD1, bS1); gll16(bD2, bS2);
    __syncthreads();
    bf16x8 af[4], bfv[4];
    #pragma unroll
    for (int i = 0; i < 4; i++) af[i]  = *(const bf16x8*)(As + aOff[i]);
    #pragma unroll
    for (int j = 0; j < 4; j++) bfv[j] = *(const bf16x8*)(Bs + bOff[j]);
    #pragma unroll
    for (int i = 0; i < 4; i++)
      #pragma unroll
      for (int j = 0; j < 4; j++)
        acc[i][j] = __builtin_amdgcn_mfma_f32_16x16x32_bf16(af[i], bfv[j], acc[i][j], 0, 0, 0);
    aS1 += 32; aS2 += 32; bS1 += 32; bS2 += 32;
  }
}

// ---------------- A-build GEMM: Acat[r][p*2048+c] = (150/2^22)*(P_p @ Q_p^T)[r][c]
__global__ __launch_bounds__(256, 2) void k_abuild(
    const unsigned short* __restrict__ tbl, unsigned short* __restrict__ Acat) {
  __shared__ __align__(16) char sm[16384];
  const int p = blockIdx.z;
  const unsigned short* P = tbl + (size_t)(2 * p) * 4194304;
  const unsigned short* Q = tbl + (size_t)(2 * p + 1) * 4194304;
  f32x4 acc[4][4];
  #pragma unroll
  for (int i = 0; i < 4; i++)
    #pragma unroll
    for (int j = 0; j < 4; j++) acc[i][j] = (f32x4){0.f, 0.f, 0.f, 0.f};
  const int m0 = blockIdx.x << 7, n0 = blockIdx.y << 7;
  gemm_core(P + (size_t)m0 * 2048, 2048, Q + (size_t)n0 * 2048, 2048, 2048,
            sm, sm + 8192, acc);
  const int tid = threadIdx.x, w = tid >> 6, l = tid & 63;
  const int quad = l >> 4, l15 = l & 15;
  const int wm = (w >> 1) << 6, wn = (w & 1) << 6;
  const float SC = 150.f / 4194304.f;
  unsigned short* Ap = Acat + (size_t)p * 2048;   // column block for this p
  #pragma unroll
  for (int j = 0; j < 4; j++) {
    int c = n0 + wn + (j << 4) + l15;
    #pragma unroll
    for (int i = 0; i < 4; i++) {
      int rb = m0 + wm + (i << 4) + (quad << 2);
      #pragma unroll
      for (int reg = 0; reg < 4; reg++)
        Ap[(size_t)(rb + reg) * 4096 + c] = f2bf(acc[i][j][reg] * SC);
    }
  }
}

// ---------------- base GEMM: out = xb @ bwb^T + bias
__global__ __launch_bounds__(256, 2) void k_base(
    const unsigned short* __restrict__ xb, const unsigned short* __restrict__ wb,
    const float* __restrict__ bias, float* __restrict__ out) {
  __shared__ __align__(16) char sm[16384];
  f32x4 acc[4][4];
  #pragma unroll
  for (int i = 0; i < 4; i++)
    #pragma unroll
    for (int j = 0; j < 4; j++) acc[i][j] = (f32x4){0.f, 0.f, 0.f, 0.f};
  const int m0 = blockIdx.x << 7, n0 = blockIdx.y << 7;
  gemm_core(xb + (size_t)m0 * 4096, 4096, wb + (size_t)n0 * 4096, 4096, 4096,
            sm, sm + 8192, acc);
  const int tid = threadIdx.x, w = tid >> 6, l = tid & 63;
  const int quad = l >> 4, l15 = l & 15;
  const int wm = (w >> 1) << 6, wn = (w & 1) << 6;
  #pragma unroll
  for (int j = 0; j < 4; j++) {
    int o = n0 + wn + (j << 4) + l15;
    float bv = bias[o];
    #pragma unroll
    for (int i = 0; i < 4; i++) {
      int mb = m0 + wm + (i << 4) + (quad << 2);
      #pragma unroll
      for (int reg = 0; reg < 4; reg++)
        out[(size_t)(mb + reg) * 4096 + o] = acc[i][j][reg] + bv;
    }
  }
}

// ---------------- pack GEMM: out[n,2r+a] += (Zg_a @ Acat^T)[n,r]
// tile: 64 n x 128 r x 2 a; K=4096; 16 KiB staged / 16 MFMA per k-step.
__global__ __launch_bounds__(256, 2) void k_pack(
    const unsigned short* __restrict__ Zg, const unsigned short* __restrict__ Acat,
    float* __restrict__ out) {
  __shared__ __align__(16) char sm[16384];
  char* Z0s = sm; char* Z1s = sm + 4096; char* Bs = sm + 8192;
  const int tid = threadIdx.x, w = tid >> 6, l = tid & 63;
  const int quad = l >> 4, l15 = l & 15;
  const int m0 = blockIdx.x << 6, r0 = blockIdx.y << 7;
  const int wm = (w >> 1) << 5, wn = (w & 1) << 6;

  // staging chunk ids: Z tiles 256 chunks (1/thread), B tile 512 (2/thread)
  int c1 = (w << 6) + l, c2 = c1 + 256;
  int rz = c1 >> 2, qz = (c1 & 3) ^ ((rz >> 1) & 3);
  int rb1 = c1 >> 2, qb1 = qz;
  int rb2 = c2 >> 2, qb2 = (c2 & 3) ^ ((rb2 >> 1) & 3);

  const unsigned short* z0S = Zg + (size_t)(m0 + rz) * 4096 + (qz << 3);
  const unsigned short* z1S = z0S + 33554432;         // a=1 plane
  const unsigned short* bS1 = Acat + (size_t)(r0 + rb1) * 4096 + (qb1 << 3);
  const unsigned short* bS2 = Acat + (size_t)(r0 + rb2) * 4096 + (qb2 << 3);
  char* z0D = Z0s + (w << 10);
  char* z1D = Z1s + (w << 10);
  char* bD1 = Bs + (w << 10);
  char* bD2 = Bs + 4096 + (w << 10);

  int zOff[2], bOff[4];
  #pragma unroll
  for (int i = 0; i < 2; i++) {
    int ra = wm + (i << 4) + l15;
    zOff[i] = (ra << 6) + ((quad ^ ((ra >> 1) & 3)) << 4);
  }
  #pragma unroll
  for (int j = 0; j < 4; j++) {
    int rb = wn + (j << 4) + l15;
    bOff[j] = (rb << 6) + ((quad ^ ((rb >> 1) & 3)) << 4);
  }

  f32x4 acc[2][2][4];   // [a][i][j]
  #pragma unroll
  for (int a = 0; a < 2; a++)
    #pragma unroll
    for (int i = 0; i < 2; i++)
      #pragma unroll
      for (int j = 0; j < 4; j++) acc[a][i][j] = (f32x4){0.f, 0.f, 0.f, 0.f};

  for (int kt = 0; kt < 4096; kt += 32) {
    __syncthreads();
    gll16(z0D, z0S); gll16(z1D, z1S);
    gll16(bD1, bS1); gll16(bD2, bS2);
    __syncthreads();
    bf16x8 zf0[2], zf1[2], bfr[4];
    #pragma unroll
    for (int i = 0; i < 2; i++) {
      zf0[i] = *(const bf16x8*)(Z0s + zOff[i]);
      zf1[i] = *(const bf16x8*)(Z1s + zOff[i]);
    }
    #pragma unroll
    for (int j = 0; j < 4; j++) bfr[j] = *(const bf16x8*)(Bs + bOff[j]);
    #pragma unroll
    for (int i = 0; i < 2; i++)
      #pragma unroll
      for (int j = 0; j < 4; j++) {
        acc[0][i][j] = __builtin_amdgcn_mfma_f32_16x16x32_bf16(zf0[i], bfr[j], acc[0][i][j], 0, 0, 0);
        acc[1][i][j] = __builtin_amdgcn_mfma_f32_16x16x32_bf16(zf1[i], bfr[j], acc[1][i][j], 0, 0, 0);
      }
    z0S += 32; z1S += 32; bS1 += 32; bS2 += 32;
  }

  // epilogue: o = 2r+a -> contiguous float2 RMW per lane (16 lanes = 128 B)
  #pragma unroll
  for (int i = 0; i < 2; i++)
    #pragma unroll
    for (int reg = 0; reg < 4; reg++) {
      size_t n = m0 + wm + (i << 4) + (quad << 2) + reg;
      #pragma unroll
      for (int j = 0; j < 4; j++) {
        int r = r0 + wn + (j << 4) + l15;
        float2* po = (float2*)(out + n * 4096 + 2 * r);
        float2 v = *po;
        v.x += acc[0][i][j][reg];
        v.y += acc[1][i][j][reg];
        *po = v;
      }
    }
}

// ---------------------------------------------------------------------------
extern "C" void kernel_launch(void* const* d_in, const int* in_sizes, int n_in,
                              void* d_out, int out_size, void* d_ws, size_t ws_size,
                              hipStream_t stream) {
  const float* x    = (const float*)d_in[0];
  const float* basw = (const float*)d_in[1];
  const float* basb = (const float*)d_in[2];
  const float* spec = (const float*)d_in[3];
  const float* Bl   = (const float*)d_in[4];
  const float* gp   = (const float*)d_in[5];
  const int*   idx  = (const int*)d_in[6];
  const int*   gidx = (const int*)d_in[7];
  const int NFP = in_sizes[3] / 2;   // 1000
  const int NG  = in_sizes[5];       // 819

  char* ws = (char*)d_ws;
  float*          gbuf  = (float*)(ws);
  float*          gatem = (float*)(ws + (64ull << 10));
  unsigned short* Acat  = (unsigned short*)(ws + (1ull << 20));
  unsigned short* xb    = (unsigned short*)(ws + (32ull << 20));
  unsigned short* bwb   = (unsigned short*)(ws + (96ull << 20));
  unsigned short* Zg    = (unsigned short*)(ws + (128ull << 20));
  unsigned short* tbl   = (unsigned short*)(ws + (128ull << 20)); // overlaps Zg (ordered)
  float* outp = (float*)d_out;

  k_gatem <<<32, 256, 0, stream>>>(gp, gidx, gatem, NG);
  k_tables<<<dim3(16384, 4), 256, 0, stream>>>(spec, idx, tbl, NFP);
  k_abuild<<<dim3(16, 16, 2), 256, 0, stream>>>(tbl, Acat);      // reads tbl
  k_gate  <<<2048, 256, 0, stream>>>(x, gatem, gbuf);            // g before convx
  k_convx <<<16384, 256, 0, stream>>>(x, xb, Zg, Bl, gbuf);      // overwrites tbl region
  k_convw <<<8192, 256, 0, stream>>>(basw, bwb);
  k_base  <<<dim3(64, 32), 256, 0, stream>>>(xb, bwb, basb, outp);
  k_pack  <<<dim3(128, 16), 256, 0, stream>>>(Zg, Acat, outp);
  (void)n_in; (void)out_size; (void)ws_size;
}

// Round 3
// 1117.787 us; speedup vs baseline: 1.1491x; 1.0595x over previous
//
#include <hip/hip_runtime.h>

// ---------------------------------------------------------------------------
// KronFTLinear: out = x@W^T + b + sum_p g[n,p] * (x @ (150*kron(A_p,B_p))^T)
//   Kron trick: out_p[n,2r+a] = 150 * sum_c A_p[r,c]*y_pa[n,c],
//               y_pa[n,c] = B_p[a,0]*x[n,2c] + B_p[a,1]*x[n,2c+1]
//   Gate folded into Y (Zg = g[n,p]*Y), p concatenated along K:
//       out_pack[n,2r+a] = sum_{k<4096} Zg_a[n,k] * Acat[r,k]
//   R2: grid orientation — weight-tile index varies FASTEST on both GEMMs so
//   co-resident blocks share the activation slice (LLC-resident working set).
// Workspace layout (256 MiB):
//   [0,64K)      g[8192][2] f32
//   [64K,96K)    gate_m[2][4096] f32
//   [1M,17M)     Acat[2048][4096] bf16  (150/2^22 folded in)
//   [32M,96M)    xb[8192][4096] bf16
//   [96M,128M)   bwb[4096][4096] bf16
//   [128M,256M)  Zg[2][8192][4096] bf16   (index: a)
//   [128M,160M)  trig tables (overlap Zg; consumed by k_abuild before k_convx)
// ---------------------------------------------------------------------------

#define AS1 __attribute__((address_space(1)))
#define AS3 __attribute__((address_space(3)))

using bf16x8   = __attribute__((ext_vector_type(8))) __bf16;
using f32x4    = __attribute__((ext_vector_type(4))) float;
using ushort8v = __attribute__((ext_vector_type(8))) unsigned short;
using ushort4v = __attribute__((ext_vector_type(4))) unsigned short;

__device__ __forceinline__ unsigned short f2bf(float f) {
  unsigned int u = __float_as_uint(f);
  u += 0x7FFFu + ((u >> 16) & 1u);   // round-to-nearest-even
  return (unsigned short)(u >> 16);
}

__device__ __forceinline__ void gll16(void* lds, const void* g) {
  __builtin_amdgcn_global_load_lds((AS1 void*)(g), (AS3 void*)(lds), 16, 0, 0);
}

// ---------------- prep: gate_m[e][d]
__global__ void k_gatem(const float* __restrict__ gp, const int* __restrict__ gidx,
                        float* __restrict__ gatem, int NG) {
  int t = blockIdx.x * 256 + threadIdx.x;    // 8192 threads
  int e = t >> 12, d = t & 4095;
  float acc = 0.f;
  for (int k = 0; k < NG; k++) {
    int iv = gidx[k];
    int dk = iv & 4095;
    float th = (float)((d * dk) & 4095) * 1.5339807878856412e-3f;  // 2pi/4096
    float cv = __cosf(th);
    float v = gp[k] * cv;
    acc += ((e & (iv >> 12)) & 1) ? -v : v;
  }
  gatem[t] = acc * (1.f / 8192.f);
}

// ---------------- prep: trig tables, z = p*2 + isQ; [z][r(2048)][kk(2048)] bf16
__global__ void k_tables(const float* __restrict__ spec, const int* __restrict__ idx,
                         unsigned short* __restrict__ tbl, int NFP) {
  int z = blockIdx.y;
  int p = z >> 1, isQ = z & 1;
  int t = blockIdx.x * 256 + threadIdx.x;
  int r = t >> 11, kk = t & 2047;
  unsigned short v = 0;
  if (kk < 2 * NFP) {
    int j = (kk < NFP) ? kk : kk - NFP;
    int iv = idx[p * NFP + j];
    int f = isQ ? (iv & 2047) : (iv >> 11);
    float th = (float)((r * f) & 2047) * 3.0679615757712823e-3f;   // 2pi/2048
    float val = (kk < NFP) ? __cosf(th) : __sinf(th);
    if (isQ) {
      float s = spec[p * NFP + j];
      val *= (kk < NFP) ? s : -s;            // A = P_cos Q_cos^T - P_sin Q_sin^T
    }
    v = f2bf(val);
  }
  tbl[(size_t)z * 4194304 + t] = v;
}

// ---------------- prep: gate logits GEMV + softmax -> g[n][2]
__global__ void k_gate(const float* __restrict__ x, const float* __restrict__ gatem,
                       float* __restrict__ g) {
  int n = blockIdx.x * 4 + (threadIdx.x >> 6);
  int l = threadIdx.x & 63;
  const float4* xr  = (const float4*)(x + (size_t)n * 4096);
  const float4* g0p = (const float4*)(gatem);
  const float4* g1p = (const float4*)(gatem + 4096);
  float s0 = 0.f, s1 = 0.f;
  for (int t = 0; t < 16; t++) {
    int ii = l + (t << 6);
    float4 xv = xr[ii], a = g0p[ii], b = g1p[ii];
    s0 += xv.x * a.x + xv.y * a.y + xv.z * a.z + xv.w * a.w;
    s1 += xv.x * b.x + xv.y * b.y + xv.z * b.z + xv.w * b.w;
  }
  for (int off = 32; off > 0; off >>= 1) {
    s0 += __shfl_down(s0, off);
    s1 += __shfl_down(s1, off);
  }
  if (l == 0) {
    float mx = fmaxf(s0, s1);
    float e0 = __expf(s0 - mx), e1 = __expf(s1 - mx);
    float inv = 1.f / (e0 + e1);
    g[2 * n] = e0 * inv;
    g[2 * n + 1] = e1 * inv;
  }
}

// ---------------- prep: x->xb bf16; Zg[a][n][p*2048+c] = g[n,p]*(B[p,a,0]x[n,2c]+B[p,a,1]x[n,2c+1])
__global__ void k_convx(const float* __restrict__ x, unsigned short* __restrict__ xb,
                        unsigned short* __restrict__ Zg, const float* __restrict__ Bl,
                        const float* __restrict__ g) {
  size_t t = (size_t)blockIdx.x * 256 + threadIdx.x;   // < 4194304, 8 elems each
  const float4* xp = (const float4*)x + t * 2;
  float4 v0 = xp[0], v1 = xp[1];
  ushort8v xv;
  xv[0]=f2bf(v0.x); xv[1]=f2bf(v0.y); xv[2]=f2bf(v0.z); xv[3]=f2bf(v0.w);
  xv[4]=f2bf(v1.x); xv[5]=f2bf(v1.y); xv[6]=f2bf(v1.z); xv[7]=f2bf(v1.w);
  *(ushort8v*)(xb + t * 8) = xv;
  int n = (int)(t >> 9);
  int c0 = ((int)t & 511) * 4;
  float gg[2] = {g[2 * n], g[2 * n + 1]};
  float xe[4] = {v0.x, v0.z, v1.x, v1.z};
  float xo[4] = {v0.y, v0.w, v1.y, v1.w};
  #pragma unroll
  for (int pa = 0; pa < 4; pa++) {
    int p = pa >> 1, a = pa & 1;
    float b0 = Bl[pa * 2] * gg[p], b1 = Bl[pa * 2 + 1] * gg[p];
    ushort4v yv;
    #pragma unroll
    for (int c = 0; c < 4; c++) yv[c] = f2bf(b0 * xe[c] + b1 * xo[c]);
    *(ushort4v*)(Zg + (size_t)a * 33554432 + (size_t)n * 4096 + p * 2048 + c0) = yv;
  }
}

// ---------------- prep: base_w -> bf16
__global__ void k_convw(const float* __restrict__ w, unsigned short* __restrict__ wb) {
  size_t t = (size_t)blockIdx.x * 256 + threadIdx.x;   // < 2097152
  const float4* sp = (const float4*)w + t * 2;
  float4 v0 = sp[0], v1 = sp[1];
  ushort8v o;
  o[0]=f2bf(v0.x); o[1]=f2bf(v0.y); o[2]=f2bf(v0.z); o[3]=f2bf(v0.w);
  o[4]=f2bf(v1.x); o[5]=f2bf(v1.y); o[6]=f2bf(v1.z); o[7]=f2bf(v1.w);
  *(ushort8v*)(wb + t * 8) = o;
}

// ---------------- shared MFMA GEMM core: C(128x128) += A(128xK) * B(128xK)^T
__device__ __forceinline__ void gemm_core(
    const unsigned short* __restrict__ Amat, int lda,
    const unsigned short* __restrict__ Bmat, int ldb,
    int K, char* As, char* Bs, f32x4 acc[4][4]) {
  const int tid = threadIdx.x;
  const int w = tid >> 6, l = tid & 63;
  const int quad = l >> 4, l15 = l & 15;
  const int wm = (w >> 1) << 6, wn = (w & 1) << 6;

  int c1 = (w << 6) + l, c2 = c1 + 256;
  int r1 = c1 >> 2, q1 = (c1 & 3) ^ ((r1 >> 1) & 3);
  int r2 = c2 >> 2, q2 = (c2 & 3) ^ ((r2 >> 1) & 3);
  const unsigned short* aS1 = Amat + (size_t)r1 * lda + (q1 << 3);
  const unsigned short* aS2 = Amat + (size_t)r2 * lda + (q2 << 3);
  const unsigned short* bS1 = Bmat + (size_t)r1 * ldb + (q1 << 3);
  const unsigned short* bS2 = Bmat + (size_t)r2 * ldb + (q2 << 3);
  char* aD1 = As + (w << 10);
  char* aD2 = As + 4096 + (w << 10);
  char* bD1 = Bs + (w << 10);
  char* bD2 = Bs + 4096 + (w << 10);

  int aOff[4], bOff[4];
  #pragma unroll
  for (int i = 0; i < 4; i++) {
    int ra = wm + (i << 4) + l15;
    aOff[i] = (ra << 6) + ((quad ^ ((ra >> 1) & 3)) << 4);
    int rb = wn + (i << 4) + l15;
    bOff[i] = (rb << 6) + ((quad ^ ((rb >> 1) & 3)) << 4);
  }

  for (int kt = 0; kt < K; kt += 32) {
    __syncthreads();
    gll16(aD1, aS1); gll16(aD2, aS2);
    gll16(bD1, bS1); gll16(bD2, bS2);
    __syncthreads();
    bf16x8 af[4], bfv[4];
    #pragma unroll
    for (int i = 0; i < 4; i++) af[i]  = *(const bf16x8*)(As + aOff[i]);
    #pragma unroll
    for (int j = 0; j < 4; j++) bfv[j] = *(const bf16x8*)(Bs + bOff[j]);
    #pragma unroll
    for (int i = 0; i < 4; i++)
      #pragma unroll
      for (int j = 0; j < 4; j++)
        acc[i][j] = __builtin_amdgcn_mfma_f32_16x16x32_bf16(af[i], bfv[j], acc[i][j], 0, 0, 0);
    aS1 += 32; aS2 += 32; bS1 += 32; bS2 += 32;
  }
}

// ---------------- A-build GEMM: Acat[r][p*2048+c] = (150/2^22)*(P_p @ Q_p^T)[r][c]
__global__ __launch_bounds__(256, 2) void k_abuild(
    const unsigned short* __restrict__ tbl, unsigned short* __restrict__ Acat) {
  __shared__ __align__(16) char sm[16384];
  const int p = blockIdx.z;
  const unsigned short* P = tbl + (size_t)(2 * p) * 4194304;
  const unsigned short* Q = tbl + (size_t)(2 * p + 1) * 4194304;
  f32x4 acc[4][4];
  #pragma unroll
  for (int i = 0; i < 4; i++)
    #pragma unroll
    for (int j = 0; j < 4; j++) acc[i][j] = (f32x4){0.f, 0.f, 0.f, 0.f};
  const int m0 = blockIdx.x << 7, n0 = blockIdx.y << 7;
  gemm_core(P + (size_t)m0 * 2048, 2048, Q + (size_t)n0 * 2048, 2048, 2048,
            sm, sm + 8192, acc);
  const int tid = threadIdx.x, w = tid >> 6, l = tid & 63;
  const int quad = l >> 4, l15 = l & 15;
  const int wm = (w >> 1) << 6, wn = (w & 1) << 6;
  const float SC = 150.f / 4194304.f;
  unsigned short* Ap = Acat + (size_t)p * 2048;   // column block for this p
  #pragma unroll
  for (int j = 0; j < 4; j++) {
    int c = n0 + wn + (j << 4) + l15;
    #pragma unroll
    for (int i = 0; i < 4; i++) {
      int rb = m0 + wm + (i << 4) + (quad << 2);
      #pragma unroll
      for (int reg = 0; reg < 4; reg++)
        Ap[(size_t)(rb + reg) * 4096 + c] = f2bf(acc[i][j][reg] * SC);
    }
  }
}

// ---------------- base GEMM: out = xb @ bwb^T + bias
// R2: blockIdx.x = o-tile (fast), blockIdx.y = m-tile -> co-resident blocks
// share the xb slice; bwb (32 MiB) LLC-resident.
__global__ __launch_bounds__(256, 2) void k_base(
    const unsigned short* __restrict__ xb, const unsigned short* __restrict__ wb,
    const float* __restrict__ bias, float* __restrict__ out) {
  __shared__ __align__(16) char sm[16384];
  f32x4 acc[4][4];
  #pragma unroll
  for (int i = 0; i < 4; i++)
    #pragma unroll
    for (int j = 0; j < 4; j++) acc[i][j] = (f32x4){0.f, 0.f, 0.f, 0.f};
  const int m0 = blockIdx.y << 7, n0 = blockIdx.x << 7;
  gemm_core(xb + (size_t)m0 * 4096, 4096, wb + (size_t)n0 * 4096, 4096, 4096,
            sm, sm + 8192, acc);
  const int tid = threadIdx.x, w = tid >> 6, l = tid & 63;
  const int quad = l >> 4, l15 = l & 15;
  const int wm = (w >> 1) << 6, wn = (w & 1) << 6;
  #pragma unroll
  for (int j = 0; j < 4; j++) {
    int o = n0 + wn + (j << 4) + l15;
    float bv = bias[o];
    #pragma unroll
    for (int i = 0; i < 4; i++) {
      int mb = m0 + wm + (i << 4) + (quad << 2);
      #pragma unroll
      for (int reg = 0; reg < 4; reg++)
        out[(size_t)(mb + reg) * 4096 + o] = acc[i][j][reg] + bv;
    }
  }
}

// ---------------- pack GEMM: out[n,2r+a] += (Zg_a @ Acat^T)[n,r]
// tile: 64 n x 128 r x 2 a; K=4096; 16 KiB staged / 16 MFMA per k-step.
// R2: blockIdx.x = r-tile (fast), blockIdx.y = m-tile.
__global__ __launch_bounds__(256, 2) void k_pack(
    const unsigned short* __restrict__ Zg, const unsigned short* __restrict__ Acat,
    float* __restrict__ out) {
  __shared__ __align__(16) char sm[16384];
  char* Z0s = sm; char* Z1s = sm + 4096; char* Bs = sm + 8192;
  const int tid = threadIdx.x, w = tid >> 6, l = tid & 63;
  const int quad = l >> 4, l15 = l & 15;
  const int m0 = blockIdx.y << 6, r0 = blockIdx.x << 7;
  const int wm = (w >> 1) << 5, wn = (w & 1) << 6;

  int c1 = (w << 6) + l, c2 = c1 + 256;
  int rz = c1 >> 2, qz = (c1 & 3) ^ ((rz >> 1) & 3);
  int rb1 = c1 >> 2, qb1 = qz;
  int rb2 = c2 >> 2, qb2 = (c2 & 3) ^ ((rb2 >> 1) & 3);

  const unsigned short* z0S = Zg + (size_t)(m0 + rz) * 4096 + (qz << 3);
  const unsigned short* z1S = z0S + 33554432;         // a=1 plane
  const unsigned short* bS1 = Acat + (size_t)(r0 + rb1) * 4096 + (qb1 << 3);
  const unsigned short* bS2 = Acat + (size_t)(r0 + rb2) * 4096 + (qb2 << 3);
  char* z0D = Z0s + (w << 10);
  char* z1D = Z1s + (w << 10);
  char* bD1 = Bs + (w << 10);
  char* bD2 = Bs + 4096 + (w << 10);

  int zOff[2], bOff[4];
  #pragma unroll
  for (int i = 0; i < 2; i++) {
    int ra = wm + (i << 4) + l15;
    zOff[i] = (ra << 6) + ((quad ^ ((ra >> 1) & 3)) << 4);
  }
  #pragma unroll
  for (int j = 0; j < 4; j++) {
    int rb = wn + (j << 4) + l15;
    bOff[j] = (rb << 6) + ((quad ^ ((rb >> 1) & 3)) << 4);
  }

  f32x4 acc[2][2][4];   // [a][i][j]
  #pragma unroll
  for (int a = 0; a < 2; a++)
    #pragma unroll
    for (int i = 0; i < 2; i++)
      #pragma unroll
      for (int j = 0; j < 4; j++) acc[a][i][j] = (f32x4){0.f, 0.f, 0.f, 0.f};

  for (int kt = 0; kt < 4096; kt += 32) {
    __syncthreads();
    gll16(z0D, z0S); gll16(z1D, z1S);
    gll16(bD1, bS1); gll16(bD2, bS2);
    __syncthreads();
    bf16x8 zf0[2], zf1[2], bfr[4];
    #pragma unroll
    for (int i = 0; i < 2; i++) {
      zf0[i] = *(const bf16x8*)(Z0s + zOff[i]);
      zf1[i] = *(const bf16x8*)(Z1s + zOff[i]);
    }
    #pragma unroll
    for (int j = 0; j < 4; j++) bfr[j] = *(const bf16x8*)(Bs + bOff[j]);
    #pragma unroll
    for (int i = 0; i < 2; i++)
      #pragma unroll
      for (int j = 0; j < 4; j++) {
        acc[0][i][j] = __builtin_amdgcn_mfma_f32_16x16x32_bf16(zf0[i], bfr[j], acc[0][i][j], 0, 0, 0);
        acc[1][i][j] = __builtin_amdgcn_mfma_f32_16x16x32_bf16(zf1[i], bfr[j], acc[1][i][j], 0, 0, 0);
      }
    z0S += 32; z1S += 32; bS1 += 32; bS2 += 32;
  }

  // epilogue: o = 2r+a -> contiguous float2 RMW per lane (16 lanes = 128 B)
  #pragma unroll
  for (int i = 0; i < 2; i++)
    #pragma unroll
    for (int reg = 0; reg < 4; reg++) {
      size_t n = m0 + wm + (i << 4) + (quad << 2) + reg;
      #pragma unroll
      for (int j = 0; j < 4; j++) {
        int r = r0 + wn + (j << 4) + l15;
        float2* po = (float2*)(out + n * 4096 + 2 * r);
        float2 v = *po;
        v.x += acc[0][i][j][reg];
        v.y += acc[1][i][j][reg];
        *po = v;
      }
    }
}

// ---------------------------------------------------------------------------
extern "C" void kernel_launch(void* const* d_in, const int* in_sizes, int n_in,
                              void* d_out, int out_size, void* d_ws, size_t ws_size,
                              hipStream_t stream) {
  const float* x    = (const float*)d_in[0];
  const float* basw = (const float*)d_in[1];
  const float* basb = (const float*)d_in[2];
  const float* spec = (const float*)d_in[3];
  const float* Bl   = (const float*)d_in[4];
  const float* gp   = (const float*)d_in[5];
  const int*   idx  = (const int*)d_in[6];
  const int*   gidx = (const int*)d_in[7];
  const int NFP = in_sizes[3] / 2;   // 1000
  const int NG  = in_sizes[5];       // 819

  char* ws = (char*)d_ws;
  float*          gbuf  = (float*)(ws);
  float*          gatem = (float*)(ws + (64ull << 10));
  unsigned short* Acat  = (unsigned short*)(ws + (1ull << 20));
  unsigned short* xb    = (unsigned short*)(ws + (32ull << 20));
  unsigned short* bwb   = (unsigned short*)(ws + (96ull << 20));
  unsigned short* Zg    = (unsigned short*)(ws + (128ull << 20));
  unsigned short* tbl   = (unsigned short*)(ws + (128ull << 20)); // overlaps Zg (ordered)
  float* outp = (float*)d_out;

  k_gatem <<<32, 256, 0, stream>>>(gp, gidx, gatem, NG);
  k_tables<<<dim3(16384, 4), 256, 0, stream>>>(spec, idx, tbl, NFP);
  k_abuild<<<dim3(16, 16, 2), 256, 0, stream>>>(tbl, Acat);      // reads tbl
  k_gate  <<<2048, 256, 0, stream>>>(x, gatem, gbuf);            // g before convx
  k_convx <<<16384, 256, 0, stream>>>(x, xb, Zg, Bl, gbuf);      // overwrites tbl region
  k_convw <<<8192, 256, 0, stream>>>(basw, bwb);
  k_base  <<<dim3(32, 64), 256, 0, stream>>>(xb, bwb, basb, outp);
  k_pack  <<<dim3(16, 128), 256, 0, stream>>>(Zg, Acat, outp);
  (void)n_in; (void)out_size; (void)ws_size;
}